// Round 1
// baseline (671.909 us; speedup 1.0000x reference)
//
#include <hip/hip_runtime.h>
#include <hip/hip_bf16.h>
#include <stdint.h>

#define NN 50000
#define NE 800000
#define NR 16

typedef unsigned short u16;
typedef unsigned int u32;

typedef __bf16 bf16x8 __attribute__((ext_vector_type(8)));
typedef float f32x4 __attribute__((ext_vector_type(4)));

__device__ __forceinline__ u16 f2bf(float f) {
  u32 u = __float_as_uint(f);
  u = u + 0x7FFFu + ((u >> 16) & 1u);
  return (u16)(u >> 16);
}

// ---------------- edge sort by dst (counting sort) ----------------
__global__ void hist_kernel(const int* __restrict__ dst, int* __restrict__ counts) {
  int e = blockIdx.x * 256 + threadIdx.x;
  if (e < NE) atomicAdd(&counts[dst[e]], 1);
}

// single block, 1024 threads: exclusive scan of counts -> starts (NN+1), counts becomes cursor
__global__ void scan_kernel(int* __restrict__ counts, int* __restrict__ starts) {
  __shared__ int buf[1024];
  int t = threadIdx.x;
  const int CH = (NN + 1023) / 1024; // 49
  int base = t * CH;
  int sum = 0;
  for (int i = 0; i < CH; ++i) {
    int idx = base + i;
    if (idx < NN) sum += counts[idx];
  }
  buf[t] = sum;
  __syncthreads();
  for (int off = 1; off < 1024; off <<= 1) {
    int x = buf[t];
    int y = (t >= off) ? buf[t - off] : 0;
    __syncthreads();
    buf[t] = x + y;
    __syncthreads();
  }
  int excl = buf[t] - sum;
  for (int i = 0; i < CH; ++i) {
    int idx = base + i;
    if (idx < NN) {
      int c = counts[idx];
      starts[idx] = excl;
      counts[idx] = excl; // cursor for scatter
      excl += c;
    }
  }
  if (t == 1023) starts[NN] = excl;
}

__global__ void scatter_kernel(const int* __restrict__ src, const int* __restrict__ dst,
                               const int* __restrict__ rel, const float* __restrict__ norm,
                               int* __restrict__ cursor, u32* __restrict__ ssr,
                               float* __restrict__ snorm) {
  int e = blockIdx.x * 256 + threadIdx.x;
  if (e < NE) {
    int d = dst[e];
    int pos = atomicAdd(&cursor[d], 1);
    ssr[pos] = ((u32)rel[e] << 16) | (u32)src[e]; // src < 50000 < 65536
    snorm[pos] = norm[e];
  }
}

// ---------------- weight convert: Wt[mat][d][k] = bf16(W[mat][k][d]) ----------------
__global__ void convert_wt(const float* __restrict__ w0, const float* __restrict__ lw0,
                           const float* __restrict__ w1, const float* __restrict__ lw1,
                           u16* __restrict__ Wt) {
  int m = blockIdx.y;
  int idx = blockIdx.x * 256 + threadIdx.x; // 0..16383
  int d = idx >> 7, k = idx & 127;
  const float* s;
  if (m < 16) s = w0 + (size_t)m * 16384;
  else if (m == 16) s = lw0;
  else if (m < 33) s = w1 + (size_t)(m - 17) * 16384;
  else s = lw1;
  Wt[(size_t)m * 16384 + idx] = f2bf(s[k * 128 + d]);
}

// ---------------- gate table: gates[r][n] = sigmoid(h[n] . gw[r]) ----------------
__global__ void gates_kernel(const float* __restrict__ h, const float* __restrict__ gw,
                             float* __restrict__ gates) {
  __shared__ float hs[16 * 132];
  __shared__ float gws[16 * 132];
  int t = threadIdx.x;
  int n0 = blockIdx.x * 16;
#pragma unroll
  for (int i = 0; i < 2; ++i) {
    int f = t + 256 * i;
    int row = f >> 5, c4 = (f & 31) * 4;
    *(float4*)&hs[row * 132 + c4] = *(const float4*)&h[(size_t)(n0 + row) * 128 + c4];
    *(float4*)&gws[row * 132 + c4] = *(const float4*)&gw[row * 128 + c4];
  }
  __syncthreads();
  int nl = t >> 4, r = t & 15;
  float s = 0.f;
#pragma unroll 8
  for (int k = 0; k < 128; ++k) s += hs[nl * 132 + k] * gws[r * 132 + k];
  gates[r * NN + n0 + nl] = 1.f / (1.f + __expf(-s));
}

// ---------------- transform: per-mat GEMM h[128-tile] @ W[mat], bf16 MFMA ----------------
// WF32=false: write bf16 into tmp[m][n][d]. WF32=true: single mat, write f32 + bias into fout.
template <bool WF32>
__global__ __launch_bounds__(256, 2)
void transform_kernel(const float* __restrict__ h, const u16* __restrict__ Wt,
                      int mat_cnt, u16* __restrict__ tmp,
                      float* __restrict__ fout, const float* __restrict__ bias) {
  __shared__ u16 As[128 * 136]; // h tile, bf16, row pad +8
  __shared__ u16 Bs[128 * 136]; // Wt tile [d][k]
  int t = threadIdx.x;
  int n0 = blockIdx.x * 128;
  // stage A (f32 -> bf16)
#pragma unroll
  for (int i = 0; i < 16; ++i) {
    int f = t + 256 * i;            // float4 index, 0..4095
    int row = f >> 5, c4 = (f & 31) * 4;
    int n = n0 + row;
    float4 v = make_float4(0.f, 0.f, 0.f, 0.f);
    if (n < NN) v = *(const float4*)&h[(size_t)n * 128 + c4];
    ushort4 u;
    u.x = f2bf(v.x); u.y = f2bf(v.y); u.z = f2bf(v.z); u.w = f2bf(v.w);
    *(ushort4*)&As[row * 136 + c4] = u;
  }
  int wave = t >> 6, lane = t & 63;
  int wr = (wave >> 1) * 64, wc = (wave & 1) * 64;
  int mrow = lane & 15, quad = lane >> 4;
  for (int m = 0; m < mat_cnt; ++m) {
    __syncthreads(); // A staged / previous mat's reads done
#pragma unroll
    for (int i = 0; i < 8; ++i) {
      int u8 = t + 256 * i;          // ushort8 index, 0..2047
      int row = u8 >> 4, c8 = (u8 & 15) * 8;
      *(uint4*)&Bs[row * 136 + c8] = *(const uint4*)&Wt[(size_t)m * 16384 + row * 128 + c8];
    }
    __syncthreads();
    f32x4 acc[4][4];
#pragma unroll
    for (int i = 0; i < 4; ++i)
#pragma unroll
      for (int j = 0; j < 4; ++j) acc[i][j] = (f32x4){0.f, 0.f, 0.f, 0.f};
#pragma unroll
    for (int kk = 0; kk < 4; ++kk) {
      int k0 = kk * 32 + quad * 8;
      bf16x8 a[4], b[4];
#pragma unroll
      for (int i = 0; i < 4; ++i) a[i] = *(const bf16x8*)&As[(wr + i * 16 + mrow) * 136 + k0];
#pragma unroll
      for (int j = 0; j < 4; ++j) b[j] = *(const bf16x8*)&Bs[(wc + j * 16 + mrow) * 136 + k0];
#pragma unroll
      for (int i = 0; i < 4; ++i)
#pragma unroll
        for (int j = 0; j < 4; ++j)
          acc[i][j] = __builtin_amdgcn_mfma_f32_16x16x32_bf16(a[i], b[j], acc[i][j], 0, 0, 0);
    }
#pragma unroll
    for (int i = 0; i < 4; ++i) {
#pragma unroll
      for (int r = 0; r < 4; ++r) {
        int row = wr + i * 16 + quad * 4 + r;
        int n = n0 + row;
        if (n < NN) {
#pragma unroll
          for (int j = 0; j < 4; ++j) {
            int col = wc + j * 16 + mrow;
            float v = acc[i][j][r];
            if (WF32) fout[(size_t)n * 128 + col] = v + bias[col];
            else tmp[((size_t)m * NN + n) * 128 + col] = f2bf(v);
          }
        }
      }
    }
  }
}

// ---------------- aggregate: one wave per dst node ----------------
__global__ __launch_bounds__(256)
void aggregate_kernel(const u32* __restrict__ tmp, const u32* __restrict__ ssr,
                      const float* __restrict__ snorm, const float* __restrict__ gates,
                      const int* __restrict__ starts, float* __restrict__ hout,
                      int mat_lo, int mat_cnt, int relu) {
  int wave = threadIdx.x >> 6, lane = threadIdx.x & 63;
  int v = blockIdx.x * 4 + wave;
  if (v >= NN) return;
  int s = starts[v], e = starts[v + 1];
  float a0 = 0.f, a1 = 0.f;
#pragma unroll 4
  for (int j = s; j < e; ++j) {
    u32 pk = ssr[j];
    int rel = (int)(pk >> 16);
    u32 rl = (u32)(rel - mat_lo);
    if (rl < (u32)mat_cnt) {
      int sn = (int)(pk & 0xFFFFu);
      float scl = snorm[j] * gates[rel * NN + sn];
      u32 w = tmp[((size_t)rl * NN + sn) * 64 + lane]; // 2 bf16 per lane
      a0 += scl * __uint_as_float(w << 16);
      a1 += scl * __uint_as_float(w & 0xFFFF0000u);
    }
  }
  float2* ho = (float2*)&hout[(size_t)v * 128 + lane * 2];
  float2 base = *ho;
  float o0 = base.x + a0, o1 = base.y + a1;
  if (relu) { o0 = fmaxf(o0, 0.f); o1 = fmaxf(o1, 0.f); }
  *ho = make_float2(o0, o1);
}

// ---------------- host ----------------
static void run_layer(const float* hin, const u16* Wt, int wt_base,
                      const float* gw, const float* bias, float* hout,
                      u16* tmp, const u32* ssr, const float* snorm,
                      float* gates, const int* starts, int mats_per_chunk,
                      int relu, hipStream_t stream) {
  gates_kernel<<<NN / 16, 256, 0, stream>>>(hin, gw, gates);
  // self-loop + bias initializes hout (f32)
  transform_kernel<true><<<(NN + 127) / 128, 256, 0, stream>>>(
      hin, Wt + (size_t)(wt_base + 16) * 16384, 1, nullptr, hout, bias);
  for (int lo = 0; lo < NR; lo += mats_per_chunk) {
    int cnt = NR - lo < mats_per_chunk ? NR - lo : mats_per_chunk;
    transform_kernel<false><<<(NN + 127) / 128, 256, 0, stream>>>(
        hin, Wt + (size_t)(wt_base + lo) * 16384, cnt, tmp, nullptr, nullptr);
    int last = (lo + cnt >= NR);
    aggregate_kernel<<<(NN + 3) / 4, 256, 0, stream>>>(
        (const u32*)tmp, ssr, snorm, gates, starts, hout, lo, cnt, relu && last);
  }
}

extern "C" void kernel_launch(void* const* d_in, const int* in_sizes, int n_in,
                              void* d_out, int out_size, void* d_ws, size_t ws_size,
                              hipStream_t stream) {
  const float* h0   = (const float*)d_in[0];
  const float* norm = (const float*)d_in[1];
  const float* w0   = (const float*)d_in[2];
  const float* b0   = (const float*)d_in[3];
  const float* lw0  = (const float*)d_in[4];
  const float* gw0  = (const float*)d_in[5];
  const float* w1   = (const float*)d_in[6];
  const float* b1   = (const float*)d_in[7];
  const float* lw1  = (const float*)d_in[8];
  const float* gw1  = (const float*)d_in[9];
  const int*   src  = (const int*)d_in[10];
  const int*   dst  = (const int*)d_in[11];
  const int*   rel  = (const int*)d_in[12];
  float* out = (float*)d_out;

  char* p = (char*)d_ws;
  auto alloc = [&](size_t bytes) -> void* {
    void* q = (void*)p;
    p += (bytes + 255) & ~(size_t)255;
    return q;
  };
  u16*   Wt     = (u16*)alloc((size_t)34 * 16384 * 2);
  float* gates  = (float*)alloc((size_t)NR * NN * 4);
  float* h1     = (float*)alloc((size_t)NN * 128 * 4);
  int*   counts = (int*)alloc((size_t)NN * 4);
  int*   starts = (int*)alloc((size_t)(NN + 1) * 4);
  u32*   ssr    = (u32*)alloc((size_t)NE * 4);
  float* snorm  = (float*)alloc((size_t)NE * 4);
  size_t used = (size_t)(p - (char*)d_ws);
  size_t per_mat = (size_t)NN * 128 * 2;
  int mats = (int)((ws_size > used ? ws_size - used : 0) / per_mat);
  if (mats > NR) mats = NR;
  if (mats < 1) mats = 1; // hope ws is at least ~50MB
  u16* tmp = (u16*)alloc((size_t)mats * per_mat);

  // ---- sort edges by dst (shared by both layers) ----
  hipMemsetAsync(counts, 0, (size_t)NN * 4, stream);
  hist_kernel<<<NE / 256, 256, 0, stream>>>(dst, counts);
  scan_kernel<<<1, 1024, 0, stream>>>(counts, starts);
  scatter_kernel<<<NE / 256, 256, 0, stream>>>(src, dst, rel, norm, counts, ssr, snorm);
  convert_wt<<<dim3(64, 34), 256, 0, stream>>>(w0, lw0, w1, lw1, Wt);

  // ---- layer 0 (relu) ----
  run_layer(h0, Wt, 0,  gw0, b0, h1,  tmp, ssr, snorm, gates, starts, mats, 1, stream);
  // ---- layer 1 (no relu) ----
  run_layer(h1, Wt, 17, gw1, b1, out, tmp, ssr, snorm, gates, starts, mats, 0, stream);
}

// Round 2
// 551.910 us; speedup vs baseline: 1.2174x; 1.2174x over previous
//
#include <hip/hip_runtime.h>
#include <hip/hip_bf16.h>
#include <stdint.h>

#define NN 50000
#define NE 800000
#define NR 16
#define SCAN_NB ((NN + 255) / 256)  // 196 blocks

typedef unsigned short u16;
typedef unsigned int u32;

typedef __bf16 bf16x8 __attribute__((ext_vector_type(8)));
typedef float f32x4 __attribute__((ext_vector_type(4)));

__device__ __forceinline__ u16 f2bf(float f) {
  u32 u = __float_as_uint(f);
  u = u + 0x7FFFu + ((u >> 16) & 1u);
  return (u16)(u >> 16);
}

// ---------------- edge sort by dst (counting sort) ----------------
__global__ void hist_kernel(const int* __restrict__ dst, int* __restrict__ counts) {
  int e = blockIdx.x * 256 + threadIdx.x;
  if (e < NE) atomicAdd(&counts[dst[e]], 1);
}

// two-level scan, stage A: per-block (256 elem) total
__global__ void scan_partial(const int* __restrict__ counts, int* __restrict__ bsum) {
  __shared__ int buf[256];
  int t = threadIdx.x;
  int i = blockIdx.x * 256 + t;
  int v = (i < NN) ? counts[i] : 0;
  buf[t] = v;
  __syncthreads();
  for (int off = 1; off < 256; off <<= 1) {
    int x = buf[t];
    int y = (t >= off) ? buf[t - off] : 0;
    __syncthreads();
    buf[t] = x + y;
    __syncthreads();
  }
  if (t == 255) bsum[blockIdx.x] = buf[255];
}

// stage B: single block scans SCAN_NB block sums -> exclusive boff; writes grand total to starts[NN]
__global__ void scan_blocksums(const int* __restrict__ bsum, int* __restrict__ boff,
                               int* __restrict__ starts) {
  __shared__ int buf[256];
  int t = threadIdx.x;
  buf[t] = (t < SCAN_NB) ? bsum[t] : 0;
  __syncthreads();
  for (int off = 1; off < 256; off <<= 1) {
    int x = buf[t];
    int y = (t >= off) ? buf[t - off] : 0;
    __syncthreads();
    buf[t] = x + y;
    __syncthreads();
  }
  if (t < SCAN_NB) boff[t] = buf[t] - bsum[t]; // exclusive
  if (t == 255) starts[NN] = buf[255];
}

// stage C: per-block exclusive rescan + block offset -> starts + cursor
__global__ void scan_final(const int* __restrict__ counts, const int* __restrict__ boff,
                           int* __restrict__ starts, int* __restrict__ cursor) {
  __shared__ int buf[256];
  int t = threadIdx.x;
  int i = blockIdx.x * 256 + t;
  int v = (i < NN) ? counts[i] : 0;
  buf[t] = v;
  __syncthreads();
  for (int off = 1; off < 256; off <<= 1) {
    int x = buf[t];
    int y = (t >= off) ? buf[t - off] : 0;
    __syncthreads();
    buf[t] = x + y;
    __syncthreads();
  }
  int s = boff[blockIdx.x] + buf[t] - v; // exclusive
  if (i < NN) {
    starts[i] = s;
    cursor[i] = s;
  }
}

__global__ void scatter_kernel(const int* __restrict__ src, const int* __restrict__ dst,
                               const int* __restrict__ rel, const float* __restrict__ norm,
                               int* __restrict__ cursor, u32* __restrict__ ssr,
                               float* __restrict__ snorm) {
  int e = blockIdx.x * 256 + threadIdx.x;
  if (e < NE) {
    int d = dst[e];
    int pos = atomicAdd(&cursor[d], 1);
    ssr[pos] = ((u32)rel[e] << 16) | (u32)src[e]; // src < 50000 < 65536
    snorm[pos] = norm[e];
  }
}

// ---------------- weight convert: Wt[mat][d][k] = bf16(W[mat][k][d]) ----------------
__global__ void convert_wt(const float* __restrict__ w0, const float* __restrict__ lw0,
                           const float* __restrict__ w1, const float* __restrict__ lw1,
                           u16* __restrict__ Wt) {
  int m = blockIdx.y;
  int idx = blockIdx.x * 256 + threadIdx.x; // 0..16383
  int d = idx >> 7, k = idx & 127;
  const float* s;
  if (m < 16) s = w0 + (size_t)m * 16384;
  else if (m == 16) s = lw0;
  else if (m < 33) s = w1 + (size_t)(m - 17) * 16384;
  else s = lw1;
  Wt[(size_t)m * 16384 + idx] = f2bf(s[k * 128 + d]);
}

// ---------------- gate table: gates[r][n] = sigmoid(h[n] . gw[r]) ----------------
__global__ void gates_kernel(const float* __restrict__ h, const float* __restrict__ gw,
                             float* __restrict__ gates) {
  __shared__ float hs[16 * 132];
  __shared__ float gws[16 * 132];
  int t = threadIdx.x;
  int n0 = blockIdx.x * 16;
#pragma unroll
  for (int i = 0; i < 2; ++i) {
    int f = t + 256 * i;
    int row = f >> 5, c4 = (f & 31) * 4;
    *(float4*)&hs[row * 132 + c4] = *(const float4*)&h[(size_t)(n0 + row) * 128 + c4];
    *(float4*)&gws[row * 132 + c4] = *(const float4*)&gw[row * 128 + c4];
  }
  __syncthreads();
  int nl = t >> 4, r = t & 15;
  float s = 0.f;
#pragma unroll 8
  for (int k = 0; k < 128; ++k) s += hs[nl * 132 + k] * gws[r * 132 + k];
  gates[r * NN + n0 + nl] = 1.f / (1.f + __expf(-s));
}

// ---------------- transform: per-mat GEMM h[128-tile] @ W[mat], bf16 MFMA ----------------
// WF32=false: write bf16 into tmp[m][n][d]. WF32=true: single mat, write f32 + bias into fout.
template <bool WF32>
__global__ __launch_bounds__(256, 2)
void transform_kernel(const float* __restrict__ h, const u16* __restrict__ Wt,
                      int mat_cnt, u16* __restrict__ tmp,
                      float* __restrict__ fout, const float* __restrict__ bias) {
  __shared__ u16 As[128 * 136]; // h tile, bf16, row pad +8
  __shared__ u16 Bs[128 * 136]; // Wt tile [d][k]
  int t = threadIdx.x;
  int n0 = blockIdx.x * 128;
  // stage A (f32 -> bf16)
#pragma unroll
  for (int i = 0; i < 16; ++i) {
    int f = t + 256 * i;            // float4 index, 0..4095
    int row = f >> 5, c4 = (f & 31) * 4;
    int n = n0 + row;
    float4 v = make_float4(0.f, 0.f, 0.f, 0.f);
    if (n < NN) v = *(const float4*)&h[(size_t)n * 128 + c4];
    ushort4 u;
    u.x = f2bf(v.x); u.y = f2bf(v.y); u.z = f2bf(v.z); u.w = f2bf(v.w);
    *(ushort4*)&As[row * 136 + c4] = u;
  }
  int wave = t >> 6, lane = t & 63;
  int wr = (wave >> 1) * 64, wc = (wave & 1) * 64;
  int mrow = lane & 15, quad = lane >> 4;
  for (int m = 0; m < mat_cnt; ++m) {
    __syncthreads(); // A staged / previous mat's reads done
#pragma unroll
    for (int i = 0; i < 8; ++i) {
      int u8 = t + 256 * i;          // ushort8 index, 0..2047
      int row = u8 >> 4, c8 = (u8 & 15) * 8;
      *(uint4*)&Bs[row * 136 + c8] = *(const uint4*)&Wt[(size_t)m * 16384 + row * 128 + c8];
    }
    __syncthreads();
    f32x4 acc[4][4];
#pragma unroll
    for (int i = 0; i < 4; ++i)
#pragma unroll
      for (int j = 0; j < 4; ++j) acc[i][j] = (f32x4){0.f, 0.f, 0.f, 0.f};
#pragma unroll
    for (int kk = 0; kk < 4; ++kk) {
      int k0 = kk * 32 + quad * 8;
      bf16x8 a[4], b[4];
#pragma unroll
      for (int i = 0; i < 4; ++i) a[i] = *(const bf16x8*)&As[(wr + i * 16 + mrow) * 136 + k0];
#pragma unroll
      for (int j = 0; j < 4; ++j) b[j] = *(const bf16x8*)&Bs[(wc + j * 16 + mrow) * 136 + k0];
#pragma unroll
      for (int i = 0; i < 4; ++i)
#pragma unroll
        for (int j = 0; j < 4; ++j)
          acc[i][j] = __builtin_amdgcn_mfma_f32_16x16x32_bf16(a[i], b[j], acc[i][j], 0, 0, 0);
    }
#pragma unroll
    for (int i = 0; i < 4; ++i) {
#pragma unroll
      for (int r = 0; r < 4; ++r) {
        int row = wr + i * 16 + quad * 4 + r;
        int n = n0 + row;
        if (n < NN) {
#pragma unroll
          for (int j = 0; j < 4; ++j) {
            int col = wc + j * 16 + mrow;
            float v = acc[i][j][r];
            if (WF32) fout[(size_t)n * 128 + col] = v + bias[col];
            else tmp[((size_t)m * NN + n) * 128 + col] = f2bf(v);
          }
        }
      }
    }
  }
}

// ---------------- aggregate: one wave per dst node ----------------
__global__ __launch_bounds__(256)
void aggregate_kernel(const u32* __restrict__ tmp, const u32* __restrict__ ssr,
                      const float* __restrict__ snorm, const float* __restrict__ gates,
                      const int* __restrict__ starts, float* __restrict__ hout,
                      int mat_lo, int mat_cnt, int relu) {
  int wave = threadIdx.x >> 6, lane = threadIdx.x & 63;
  int v = blockIdx.x * 4 + wave;
  if (v >= NN) return;
  int s = starts[v], e = starts[v + 1];
  float a0 = 0.f, a1 = 0.f;
#pragma unroll 4
  for (int j = s; j < e; ++j) {
    u32 pk = ssr[j];
    int rel = (int)(pk >> 16);
    u32 rl = (u32)(rel - mat_lo);
    if (rl < (u32)mat_cnt) {
      int sn = (int)(pk & 0xFFFFu);
      float scl = snorm[j] * gates[rel * NN + sn];
      u32 w = tmp[((size_t)rl * NN + sn) * 64 + lane]; // 2 bf16 per lane
      a0 += scl * __uint_as_float(w << 16);
      a1 += scl * __uint_as_float(w & 0xFFFF0000u);
    }
  }
  float2* ho = (float2*)&hout[(size_t)v * 128 + lane * 2];
  float2 base = *ho;
  float o0 = base.x + a0, o1 = base.y + a1;
  if (relu) { o0 = fmaxf(o0, 0.f); o1 = fmaxf(o1, 0.f); }
  *ho = make_float2(o0, o1);
}

// ---------------- host ----------------
static void run_layer(const float* hin, const u16* Wt, int wt_base,
                      const float* gw, const float* bias, float* hout,
                      u16* tmp, const u32* ssr, const float* snorm,
                      float* gates, const int* starts, int mats_per_chunk,
                      int relu, hipStream_t stream) {
  gates_kernel<<<NN / 16, 256, 0, stream>>>(hin, gw, gates);
  // self-loop + bias initializes hout (f32)
  transform_kernel<true><<<(NN + 127) / 128, 256, 0, stream>>>(
      hin, Wt + (size_t)(wt_base + 16) * 16384, 1, nullptr, hout, bias);
  for (int lo = 0; lo < NR; lo += mats_per_chunk) {
    int cnt = NR - lo < mats_per_chunk ? NR - lo : mats_per_chunk;
    transform_kernel<false><<<(NN + 127) / 128, 256, 0, stream>>>(
        hin, Wt + (size_t)(wt_base + lo) * 16384, cnt, tmp, nullptr, nullptr);
    int last = (lo + cnt >= NR);
    aggregate_kernel<<<(NN + 3) / 4, 256, 0, stream>>>(
        (const u32*)tmp, ssr, snorm, gates, starts, hout, lo, cnt, relu && last);
  }
}

extern "C" void kernel_launch(void* const* d_in, const int* in_sizes, int n_in,
                              void* d_out, int out_size, void* d_ws, size_t ws_size,
                              hipStream_t stream) {
  const float* h0   = (const float*)d_in[0];
  const float* norm = (const float*)d_in[1];
  const float* w0   = (const float*)d_in[2];
  const float* b0   = (const float*)d_in[3];
  const float* lw0  = (const float*)d_in[4];
  const float* gw0  = (const float*)d_in[5];
  const float* w1   = (const float*)d_in[6];
  const float* b1   = (const float*)d_in[7];
  const float* lw1  = (const float*)d_in[8];
  const float* gw1  = (const float*)d_in[9];
  const int*   src  = (const int*)d_in[10];
  const int*   dst  = (const int*)d_in[11];
  const int*   rel  = (const int*)d_in[12];
  float* out = (float*)d_out;

  char* p = (char*)d_ws;
  auto alloc = [&](size_t bytes) -> void* {
    void* q = (void*)p;
    p += (bytes + 255) & ~(size_t)255;
    return q;
  };
  u16*   Wt     = (u16*)alloc((size_t)34 * 16384 * 2);
  float* gates  = (float*)alloc((size_t)NR * NN * 4);
  float* h1     = (float*)alloc((size_t)NN * 128 * 4);
  int*   counts = (int*)alloc((size_t)NN * 4);
  int*   cursor = (int*)alloc((size_t)NN * 4);
  int*   starts = (int*)alloc((size_t)(NN + 1) * 4);
  int*   bsum   = (int*)alloc((size_t)256 * 4);
  int*   boff   = (int*)alloc((size_t)256 * 4);
  u32*   ssr    = (u32*)alloc((size_t)NE * 4);
  float* snorm  = (float*)alloc((size_t)NE * 4);
  size_t used = (size_t)(p - (char*)d_ws);
  size_t per_mat = (size_t)NN * 128 * 2;
  int mats = (int)((ws_size > used ? ws_size - used : 0) / per_mat);
  if (mats > NR) mats = NR;
  if (mats < 1) mats = 1; // hope ws is at least ~50MB
  u16* tmp = (u16*)alloc((size_t)mats * per_mat);

  // ---- sort edges by dst (shared by both layers) ----
  hipMemsetAsync(counts, 0, (size_t)NN * 4, stream);
  hist_kernel<<<NE / 256, 256, 0, stream>>>(dst, counts);
  scan_partial<<<SCAN_NB, 256, 0, stream>>>(counts, bsum);
  scan_blocksums<<<1, 256, 0, stream>>>(bsum, boff, starts);
  scan_final<<<SCAN_NB, 256, 0, stream>>>(counts, boff, starts, cursor);
  scatter_kernel<<<NE / 256, 256, 0, stream>>>(src, dst, rel, norm, cursor, ssr, snorm);
  convert_wt<<<dim3(64, 34), 256, 0, stream>>>(w0, lw0, w1, lw1, Wt);

  // ---- layer 0 (relu) ----
  run_layer(h0, Wt, 0,  gw0, b0, h1,  tmp, ssr, snorm, gates, starts, mats, 1, stream);
  // ---- layer 1 (no relu) ----
  run_layer(h1, Wt, 17, gw1, b1, out, tmp, ssr, snorm, gates, starts, mats, 0, stream);
}

// Round 3
// 519.959 us; speedup vs baseline: 1.2922x; 1.0614x over previous
//
#include <hip/hip_runtime.h>
#include <hip/hip_bf16.h>
#include <stdint.h>

#define NN 50000
#define NE 800000
#define NR 16
#define SCAN_NB ((NN + 255) / 256)  // 196 blocks
#define NTILES ((NN + 127) / 128)   // 391

typedef unsigned short u16;
typedef unsigned int u32;

typedef __bf16 bf16x8 __attribute__((ext_vector_type(8)));
typedef float f32x4 __attribute__((ext_vector_type(4)));

__device__ __forceinline__ u16 f2bf(float f) {
  u32 u = __float_as_uint(f);
  u = u + 0x7FFFu + ((u >> 16) & 1u);
  return (u16)(u >> 16);
}

// ---------------- edge sort by dst (counting sort) ----------------
__global__ void hist_kernel(const int* __restrict__ dst, int* __restrict__ counts) {
  int e = blockIdx.x * 256 + threadIdx.x;
  if (e < NE) atomicAdd(&counts[dst[e]], 1);
}

__global__ void scan_partial(const int* __restrict__ counts, int* __restrict__ bsum) {
  __shared__ int buf[256];
  int t = threadIdx.x;
  int i = blockIdx.x * 256 + t;
  int v = (i < NN) ? counts[i] : 0;
  buf[t] = v;
  __syncthreads();
  for (int off = 1; off < 256; off <<= 1) {
    int x = buf[t];
    int y = (t >= off) ? buf[t - off] : 0;
    __syncthreads();
    buf[t] = x + y;
    __syncthreads();
  }
  if (t == 255) bsum[blockIdx.x] = buf[255];
}

__global__ void scan_blocksums(const int* __restrict__ bsum, int* __restrict__ boff,
                               int* __restrict__ starts) {
  __shared__ int buf[256];
  int t = threadIdx.x;
  buf[t] = (t < SCAN_NB) ? bsum[t] : 0;
  __syncthreads();
  for (int off = 1; off < 256; off <<= 1) {
    int x = buf[t];
    int y = (t >= off) ? buf[t - off] : 0;
    __syncthreads();
    buf[t] = x + y;
    __syncthreads();
  }
  if (t < SCAN_NB) boff[t] = buf[t] - bsum[t]; // exclusive
  if (t == 255) starts[NN] = buf[255];
}

__global__ void scan_final(const int* __restrict__ counts, const int* __restrict__ boff,
                           int* __restrict__ starts, int* __restrict__ cursor) {
  __shared__ int buf[256];
  int t = threadIdx.x;
  int i = blockIdx.x * 256 + t;
  int v = (i < NN) ? counts[i] : 0;
  buf[t] = v;
  __syncthreads();
  for (int off = 1; off < 256; off <<= 1) {
    int x = buf[t];
    int y = (t >= off) ? buf[t - off] : 0;
    __syncthreads();
    buf[t] = x + y;
    __syncthreads();
  }
  int s = boff[blockIdx.x] + buf[t] - v; // exclusive
  if (i < NN) {
    starts[i] = s;
    cursor[i] = s;
  }
}

// esd[pos] = { rel<<16 | src, norm_bits }
__global__ void scatter_kernel(const int* __restrict__ src, const int* __restrict__ dst,
                               const int* __restrict__ rel, const float* __restrict__ norm,
                               int* __restrict__ cursor, uint2* __restrict__ esd) {
  int e = blockIdx.x * 256 + threadIdx.x;
  if (e < NE) {
    int d = dst[e];
    int pos = atomicAdd(&cursor[d], 1);
    esd[pos] = make_uint2(((u32)rel[e] << 16) | (u32)src[e], __float_as_uint(norm[e]));
  }
}

// ---------------- weight convert: Wt[mat][d][k] = bf16(W[mat][k][d]) ----------------
__global__ void convert_wt(const float* __restrict__ w0, const float* __restrict__ lw0,
                           const float* __restrict__ w1, const float* __restrict__ lw1,
                           u16* __restrict__ Wt) {
  int m = blockIdx.y;
  int idx = blockIdx.x * 256 + threadIdx.x; // 0..16383
  int d = idx >> 7, k = idx & 127;
  const float* s;
  if (m < 16) s = w0 + (size_t)m * 16384;
  else if (m == 16) s = lw0;
  else if (m < 33) s = w1 + (size_t)(m - 17) * 16384;
  else s = lw1;
  Wt[(size_t)m * 16384 + idx] = f2bf(s[k * 128 + d]);
}

// ---------------- h f32 -> bf16 ----------------
__global__ void hconv_kernel(const float* __restrict__ h, u16* __restrict__ hbf) {
  int i = blockIdx.x * 256 + threadIdx.x; // float4 index, NN*32 total
  float4 v = ((const float4*)h)[i];
  ushort4 u;
  u.x = f2bf(v.x); u.y = f2bf(v.y); u.z = f2bf(v.z); u.w = f2bf(v.w);
  ((ushort4*)hbf)[i] = u;
}

// ---------------- gate table: gates[r][n] = sigmoid(h[n] . gw[r]) ----------------
__global__ void gates_kernel(const float* __restrict__ h, const float* __restrict__ gw,
                             float* __restrict__ gates) {
  __shared__ float hs[16 * 132];
  __shared__ float gws[16 * 132];
  int t = threadIdx.x;
  int n0 = blockIdx.x * 16;
#pragma unroll
  for (int i = 0; i < 2; ++i) {
    int f = t + 256 * i;
    int row = f >> 5, c4 = (f & 31) * 4;
    *(float4*)&hs[row * 132 + c4] = *(const float4*)&h[(size_t)(n0 + row) * 128 + c4];
    *(float4*)&gws[row * 132 + c4] = *(const float4*)&gw[row * 128 + c4];
  }
  __syncthreads();
  int nl = t >> 4, r = t & 15;
  float s = 0.f;
#pragma unroll 8
  for (int k = 0; k < 128; ++k) s += hs[nl * 132 + k] * gws[r * 132 + k];
  gates[r * NN + n0 + nl] = 1.f / (1.f + __expf(-s));
}

// ---------------- transform: GEMM h[128-tile] @ W[mat], bf16 MFMA ----------------
// 2D grid: blockIdx.x = node tile, blockIdx.y = mat group (CM mats each).
// WF32=false: tmp[mm][n][d] = bf16(acc * gate[mm][n]).  WF32=true: fout = acc + bias (f32).
template <bool WF32>
__global__ __launch_bounds__(256, 2)
void transform_kernel(const u16* __restrict__ hbf, const u16* __restrict__ Wt,
                      int cnt, int CM, const float* __restrict__ gate_base,
                      u16* __restrict__ tmp, float* __restrict__ fout,
                      const float* __restrict__ bias) {
  __shared__ u16 As[128 * 136]; // h tile, bf16, row pad +8
  __shared__ u16 Bs[128 * 136]; // Wt tile [d][k]
  __shared__ float gs[128];
  int t = threadIdx.x;
  int n0 = blockIdx.x * 128;
  // stage A (already bf16: pure 16B copies)
#pragma unroll
  for (int i = 0; i < 8; ++i) {
    int u8 = t + 256 * i;           // uint4 index, 0..2047
    int row = u8 >> 4, c8 = (u8 & 15) * 8;
    int n = n0 + row;
    uint4 v = make_uint4(0, 0, 0, 0);
    if (n < NN) v = *(const uint4*)&hbf[(size_t)n * 128 + c8];
    *(uint4*)&As[row * 136 + c8] = v;
  }
  int wave = t >> 6, lane = t & 63;
  int wr = (wave >> 1) * 64, wc = (wave & 1) * 64;
  int mrow = lane & 15, quad = lane >> 4;
  int m0 = blockIdx.y * CM;
  int m1 = m0 + CM < cnt ? m0 + CM : cnt;
  for (int m = m0; m < m1; ++m) {
    __syncthreads(); // A staged / previous mat's reads done
#pragma unroll
    for (int i = 0; i < 8; ++i) {
      int u8 = t + 256 * i;
      int row = u8 >> 4, c8 = (u8 & 15) * 8;
      *(uint4*)&Bs[row * 136 + c8] = *(const uint4*)&Wt[(size_t)m * 16384 + row * 128 + c8];
    }
    if (!WF32 && t < 128) {
      int n = n0 + t;
      gs[t] = (n < NN) ? gate_base[(size_t)m * NN + n] : 0.f;
    }
    __syncthreads();
    f32x4 acc[4][4];
#pragma unroll
    for (int i = 0; i < 4; ++i)
#pragma unroll
      for (int j = 0; j < 4; ++j) acc[i][j] = (f32x4){0.f, 0.f, 0.f, 0.f};
#pragma unroll
    for (int kk = 0; kk < 4; ++kk) {
      int k0 = kk * 32 + quad * 8;
      bf16x8 a[4], b[4];
#pragma unroll
      for (int i = 0; i < 4; ++i) a[i] = *(const bf16x8*)&As[(wr + i * 16 + mrow) * 136 + k0];
#pragma unroll
      for (int j = 0; j < 4; ++j) b[j] = *(const bf16x8*)&Bs[(wc + j * 16 + mrow) * 136 + k0];
#pragma unroll
      for (int i = 0; i < 4; ++i)
#pragma unroll
        for (int j = 0; j < 4; ++j)
          acc[i][j] = __builtin_amdgcn_mfma_f32_16x16x32_bf16(a[i], b[j], acc[i][j], 0, 0, 0);
    }
#pragma unroll
    for (int i = 0; i < 4; ++i) {
#pragma unroll
      for (int r = 0; r < 4; ++r) {
        int row = wr + i * 16 + quad * 4 + r;
        int n = n0 + row;
        if (n < NN) {
          float g = WF32 ? 0.f : gs[row];
#pragma unroll
          for (int j = 0; j < 4; ++j) {
            int col = wc + j * 16 + mrow;
            float v = acc[i][j][r];
            if (WF32) fout[(size_t)n * 128 + col] = v + bias[col];
            else tmp[((size_t)m * NN + n) * 128 + col] = f2bf(v * g);
          }
        }
      }
    }
  }
}

// ---------------- aggregate: one wave per dst node, chunk-8 pipelined ----------------
template <bool FULL>
__global__ __launch_bounds__(256)
void aggregate_kernel(const u32* __restrict__ tmp, const uint2* __restrict__ esd,
                      const int* __restrict__ starts, float* __restrict__ hout,
                      int mat_lo, int mat_cnt, int relu) {
  int wave = threadIdx.x >> 6, lane = threadIdx.x & 63;
  int v = blockIdx.x * 4 + wave;
  if (v >= NN) return;
  int s = starts[v], e = starts[v + 1];
  float a0 = 0.f, a1 = 0.f;
  int j = s;
  if (FULL) {
    for (; j + 8 <= e; j += 8) {
      uint2 p[8];
      u32 w[8];
      float sc[8];
#pragma unroll
      for (int i = 0; i < 8; ++i) p[i] = esd[j + i];
#pragma unroll
      for (int i = 0; i < 8; ++i) {
        u32 rs = p[i].x; // rel<<16 | sn
        u32 off = ((rs >> 16) * (u32)NN + (rs & 0xFFFFu)) * 64u + (u32)lane;
        w[i] = tmp[off];
        sc[i] = __uint_as_float(p[i].y);
      }
#pragma unroll
      for (int i = 0; i < 8; ++i) {
        a0 = fmaf(sc[i], __uint_as_float(w[i] << 16), a0);
        a1 = fmaf(sc[i], __uint_as_float(w[i] & 0xFFFF0000u), a1);
      }
    }
  }
  for (; j < e; ++j) {
    uint2 p = esd[j];
    int rel = (int)(p.x >> 16);
    u32 rl = (u32)(rel - mat_lo);
    if (FULL || rl < (u32)mat_cnt) {
      u32 off = (rl * (u32)NN + (p.x & 0xFFFFu)) * 64u + (u32)lane;
      float sc = __uint_as_float(p.y);
      u32 w = tmp[off];
      a0 = fmaf(sc, __uint_as_float(w << 16), a0);
      a1 = fmaf(sc, __uint_as_float(w & 0xFFFF0000u), a1);
    }
  }
  float2* ho = (float2*)&hout[(size_t)v * 128 + lane * 2];
  float2 b = *ho;
  float o0 = b.x + a0, o1 = b.y + a1;
  if (relu) { o0 = fmaxf(o0, 0.f); o1 = fmaxf(o1, 0.f); }
  *ho = make_float2(o0, o1);
}

// ---------------- host ----------------
static void run_layer(const float* hin, u16* hbf, const u16* Wt, int wt_base,
                      const float* gw, const float* bias, float* hout,
                      u16* tmp, const uint2* esd, float* gates, const int* starts,
                      int mats_per_chunk, int relu, hipStream_t stream) {
  hconv_kernel<<<NN * 32 / 256, 256, 0, stream>>>(hin, hbf);
  gates_kernel<<<NN / 16, 256, 0, stream>>>(hin, gw, gates);
  // self-loop + bias initializes hout (f32)
  transform_kernel<true><<<dim3(NTILES, 1), 256, 0, stream>>>(
      hbf, Wt + (size_t)(wt_base + 16) * 16384, 1, 1, nullptr, nullptr, hout, bias);
  for (int lo = 0; lo < NR; lo += mats_per_chunk) {
    int cnt = NR - lo < mats_per_chunk ? NR - lo : mats_per_chunk;
    const int CM = 2;
    int G = (cnt + CM - 1) / CM;
    transform_kernel<false><<<dim3(NTILES, G), 256, 0, stream>>>(
        hbf, Wt + (size_t)(wt_base + lo) * 16384, cnt, CM, gates + (size_t)lo * NN,
        tmp, nullptr, nullptr);
    int last = (lo + cnt >= NR);
    if (cnt == NR)
      aggregate_kernel<true><<<(NN + 3) / 4, 256, 0, stream>>>(
          (const u32*)tmp, esd, starts, hout, 0, NR, relu && last);
    else
      aggregate_kernel<false><<<(NN + 3) / 4, 256, 0, stream>>>(
          (const u32*)tmp, esd, starts, hout, lo, cnt, relu && last);
  }
}

extern "C" void kernel_launch(void* const* d_in, const int* in_sizes, int n_in,
                              void* d_out, int out_size, void* d_ws, size_t ws_size,
                              hipStream_t stream) {
  const float* h0   = (const float*)d_in[0];
  const float* norm = (const float*)d_in[1];
  const float* w0   = (const float*)d_in[2];
  const float* b0   = (const float*)d_in[3];
  const float* lw0  = (const float*)d_in[4];
  const float* gw0  = (const float*)d_in[5];
  const float* w1   = (const float*)d_in[6];
  const float* b1   = (const float*)d_in[7];
  const float* lw1  = (const float*)d_in[8];
  const float* gw1  = (const float*)d_in[9];
  const int*   src  = (const int*)d_in[10];
  const int*   dst  = (const int*)d_in[11];
  const int*   rel  = (const int*)d_in[12];
  float* out = (float*)d_out;

  char* p = (char*)d_ws;
  auto alloc = [&](size_t bytes) -> void* {
    void* q = (void*)p;
    p += (bytes + 255) & ~(size_t)255;
    return q;
  };
  u16*   Wt     = (u16*)alloc((size_t)34 * 16384 * 2);
  float* gates  = (float*)alloc((size_t)NR * NN * 4);
  float* h1     = (float*)alloc((size_t)NN * 128 * 4);
  u16*   hbf    = (u16*)alloc((size_t)NN * 128 * 2);
  int*   counts = (int*)alloc((size_t)NN * 4);
  int*   cursor = (int*)alloc((size_t)NN * 4);
  int*   starts = (int*)alloc((size_t)(NN + 1) * 4);
  int*   bsum   = (int*)alloc((size_t)256 * 4);
  int*   boff   = (int*)alloc((size_t)256 * 4);
  uint2* esd    = (uint2*)alloc((size_t)NE * 8);
  size_t used = (size_t)(p - (char*)d_ws);
  size_t per_mat = (size_t)NN * 128 * 2;
  int mats = (int)((ws_size > used ? ws_size - used : 0) / per_mat);
  if (mats > NR) mats = NR;
  if (mats < 1) mats = 1;
  u16* tmp = (u16*)alloc((size_t)mats * per_mat);

  // ---- sort edges by dst (shared by both layers) ----
  hipMemsetAsync(counts, 0, (size_t)NN * 4, stream);
  hist_kernel<<<NE / 256, 256, 0, stream>>>(dst, counts);
  scan_partial<<<SCAN_NB, 256, 0, stream>>>(counts, bsum);
  scan_blocksums<<<1, 256, 0, stream>>>(bsum, boff, starts);
  scan_final<<<SCAN_NB, 256, 0, stream>>>(counts, boff, starts, cursor);
  scatter_kernel<<<NE / 256, 256, 0, stream>>>(src, dst, rel, norm, cursor, esd);
  convert_wt<<<dim3(64, 34), 256, 0, stream>>>(w0, lw0, w1, lw1, Wt);

  // ---- layer 0 (relu) ----
  run_layer(h0, hbf, Wt, 0,  gw0, b0, h1,  tmp, esd, gates, starts, mats, 1, stream);
  // ---- layer 1 (no relu) ----
  run_layer(h1, hbf, Wt, 17, gw1, b1, out, tmp, esd, gates, starts, mats, 0, stream);
}